// Round 3
// baseline (423.930 us; speedup 1.0000x reference)
//
#include <hip/hip_runtime.h>
#include <math.h>

#define NLEVELS 16
#define TBITS 19
#define TMASK ((1 << TBITS) - 1)

typedef float vfloat4 __attribute__((ext_vector_type(4)));  // clang-native, nt-store OK

struct Meta {
    float resf[NLEVELS];
    int   resi[NLEVELS];
    int   off[NLEVELS];   // entry offsets (in float2 units)
    unsigned hashedMask;  // bit i set -> level i hashed
    int   prime;
};

__global__ __launch_bounds__(256) void hashgrid2d_kernel(
    const float2* __restrict__ uv,
    const float2* __restrict__ lat,   // latents as float2 entries (F=2)
    float* __restrict__ out,
    Meta m, int n)
{
    int p = blockIdx.x * blockDim.x + threadIdx.x;
    if (p >= n) return;

    float2 u = uv[p];
    float o[2 * NLEVELS];

    const float* latf = (const float*)lat;

#pragma unroll
    for (int i = 0; i < NLEVELS; ++i) {
        const float rf  = m.resf[i];
        const int   ri  = m.resi[i];
        const int   off = m.off[i];

        float sx = u.x * rf;
        float sy = u.y * rf;
        float fx = floorf(sx);
        float fy = floorf(sy);
        int x0 = (int)fx;
        int y0 = (int)fy;
        float px = sx - fx;   // in [0,1)
        float py = sy - fy;

        // bilinear weights, corner order (0,0),(0,1),(1,0),(1,1)
        float wx0 = 1.0f - px, wx1 = px;
        float wy0 = 1.0f - py, wy1 = py;
        float w00 = wx0 * wy0;
        float w01 = wx0 * wy1;
        float w10 = wx1 * wy0;
        float w11 = wx1 * wy1;

        float2 v00, v01, v10, v11;

        if ((m.hashedMask >> i) & 1u) {
            // idx = (x*1 ^ y*prime) mod T ; all operands non-negative, T=2^19
            int yp0 = y0 * m.prime;
            int yp1 = yp0 + m.prime;
            int x1  = x0 + 1;
            int i00 = (x0 ^ yp0) & TMASK;
            int i01 = (x0 ^ yp1) & TMASK;
            int i10 = (x1 ^ yp0) & TMASK;
            int i11 = (x1 ^ yp1) & TMASK;
            v00 = lat[off + i00];
            v01 = lat[off + i01];
            v10 = lat[off + i10];
            v11 = lat[off + i11];
        } else {
            // dense: idx = x*res + y ; (x,y) and (x,y+1) contiguous -> one 16B load
            int base0 = off + x0 * ri + y0;   // corner (0,0); (0,1) is next entry
            int base1 = base0 + ri;           // corner (1,0); (1,1) is next entry
            float4 a, b;
            __builtin_memcpy(&a, latf + 2 * (size_t)base0, 16);  // may be 8B-aligned
            __builtin_memcpy(&b, latf + 2 * (size_t)base1, 16);
            v00 = make_float2(a.x, a.y);
            v01 = make_float2(a.z, a.w);
            v10 = make_float2(b.x, b.y);
            v11 = make_float2(b.z, b.w);
        }

        o[2 * i]     = w00 * v00.x + w01 * v01.x + w10 * v10.x + w11 * v11.x;
        o[2 * i + 1] = w00 * v00.y + w01 * v01.y + w10 * v10.y + w11 * v11.y;
    }

    // 32 contiguous floats per point -> 8x float4 NON-TEMPORAL stores.
    // Output (128 MB) has zero reuse; nt keeps L2 capacity for the latent
    // table that the hashed-level random gathers need resident.
    vfloat4* op = (vfloat4*)(out + (size_t)p * (2 * NLEVELS));
#pragma unroll
    for (int j = 0; j < 8; ++j) {
        vfloat4 w;
        w.x = o[4 * j + 0];
        w.y = o[4 * j + 1];
        w.z = o[4 * j + 2];
        w.w = o[4 * j + 3];
        __builtin_nontemporal_store(w, op + j);
    }
}

static void compute_meta(Meta& m)
{
    // EXACTLY mirror the Python reference's double-precision math:
    // b = exp((log(2048) - log(16)) / 15); res_i = int(16 * b**i)
    const double b = exp((log(2048.0) - log(16.0)) / 15.0);
    int off = 0;
    unsigned mask = 0;
    const long long T = 1LL << TBITS;
    for (int i = 0; i < NLEVELS; ++i) {
        int res = (int)(16.0 * pow(b, (double)i));
        long long n_entries = (long long)(res + 1) * (long long)(res + 1);
        if (n_entries > T) {
            n_entries = T;
            mask |= (1u << i);
        }
        m.resf[i] = (float)res;
        m.resi[i] = res;
        m.off[i]  = off;
        off += (int)n_entries;
    }
    m.hashedMask = mask;

    // smallest prime >= 2^17
    int pr = 1 << 17;
    for (;;) {
        bool isp = true;
        for (long long q = 2; q * q <= pr; ++q)
            if (pr % q == 0) { isp = false; break; }
        if (isp) break;
        ++pr;
    }
    m.prime = pr;
}

extern "C" void kernel_launch(void* const* d_in, const int* in_sizes, int n_in,
                              void* d_out, int out_size, void* d_ws, size_t ws_size,
                              hipStream_t stream)
{
    const float2* uv  = (const float2*)d_in[0];
    const float2* lat = (const float2*)d_in[1];
    float* out = (float*)d_out;

    int n = in_sizes[0] / 2;  // number of points

    Meta m;
    compute_meta(m);

    const int block = 256;
    const int grid = (n + block - 1) / block;
    hashgrid2d_kernel<<<grid, block, 0, stream>>>(uv, lat, out, m, n);
}

// Round 4
// 356.983 us; speedup vs baseline: 1.1875x; 1.1875x over previous
//
#include <hip/hip_runtime.h>
#include <math.h>

#define NLEVELS 16
#define NDENSE 12   // levels 0-11: (res+1)^2 <= 2^19, dense (structurally stable)
#define NHASH 4     // levels 12-15: hashed
#define TBITS 19
#define TMASK ((1 << TBITS) - 1)

typedef float vfloat4 __attribute__((ext_vector_type(4)));

struct Meta {
    float resf[NLEVELS];
    int   resi[NLEVELS];
    int   off[NLEVELS];   // entry offsets (in float2 units)
    int   prime;
};

__global__ __launch_bounds__(256, 2) void hashgrid2d_kernel(
    const float2* __restrict__ uv,
    const float2* __restrict__ lat,   // latents as float2 entries (F=2)
    float* __restrict__ out,
    Meta m, int n)
{
    int p = blockIdx.x * blockDim.x + threadIdx.x;
    if (p >= n) return;

    float2 u = uv[p];
    const float* latf = (const float*)lat;

    // Per-level latent data, statically indexed so it lives in registers.
    float4 da[NDENSE];      // dense corners (x0,y0),(x0,y1)
    float4 db[NDENSE];      // dense corners (x1,y0),(x1,y1)
    float2 hv[NHASH][4];    // hashed corners

    // ---- Phase 1: compute addresses and ISSUE ALL 40 LOADS ----
    // (latency-bound kernel: maximize loads in flight per wave)
#pragma unroll
    for (int i = 0; i < NDENSE; ++i) {
        float sx = u.x * m.resf[i];
        float sy = u.y * m.resf[i];
        int x0 = (int)floorf(sx);
        int y0 = (int)floorf(sy);
        int base0 = m.off[i] + x0 * m.resi[i] + y0;  // (x0,y0); (x0,y1) adjacent
        int base1 = base0 + m.resi[i];               // (x1,y0); (x1,y1) adjacent
        __builtin_memcpy(&da[i], latf + 2 * (size_t)base0, 16);  // 8B-aligned 16B load
        __builtin_memcpy(&db[i], latf + 2 * (size_t)base1, 16);
    }
#pragma unroll
    for (int h = 0; h < NHASH; ++h) {
        int i = NDENSE + h;
        float sx = u.x * m.resf[i];
        float sy = u.y * m.resf[i];
        int x0 = (int)floorf(sx);
        int y0 = (int)floorf(sy);
        int yp0 = y0 * m.prime;
        int yp1 = yp0 + m.prime;
        int x1  = x0 + 1;
        const float2* tbl = lat + m.off[i];
        hv[h][0] = tbl[(x0 ^ yp0) & TMASK];
        hv[h][1] = tbl[(x0 ^ yp1) & TMASK];
        hv[h][2] = tbl[(x1 ^ yp0) & TMASK];
        hv[h][3] = tbl[(x1 ^ yp1) & TMASK];
    }

    // ---- Phase 2: weights + weighted sums, in ISSUE ORDER (incremental vmcnt) ----
    float o[2 * NLEVELS];
#pragma unroll
    for (int i = 0; i < NDENSE; ++i) {
        float sx = u.x * m.resf[i];
        float sy = u.y * m.resf[i];
        float fx = floorf(sx), fy = floorf(sy);
        float px = sx - fx,   py = sy - fy;
        float w00 = (1.0f - px) * (1.0f - py);
        float w01 = (1.0f - px) * py;
        float w10 = px * (1.0f - py);
        float w11 = px * py;
        o[2*i]   = w00 * da[i].x + w01 * da[i].z + w10 * db[i].x + w11 * db[i].z;
        o[2*i+1] = w00 * da[i].y + w01 * da[i].w + w10 * db[i].y + w11 * db[i].w;
    }
#pragma unroll
    for (int h = 0; h < NHASH; ++h) {
        int i = NDENSE + h;
        float sx = u.x * m.resf[i];
        float sy = u.y * m.resf[i];
        float fx = floorf(sx), fy = floorf(sy);
        float px = sx - fx,   py = sy - fy;
        float w00 = (1.0f - px) * (1.0f - py);
        float w01 = (1.0f - px) * py;
        float w10 = px * (1.0f - py);
        float w11 = px * py;
        o[2*i]   = w00 * hv[h][0].x + w01 * hv[h][1].x + w10 * hv[h][2].x + w11 * hv[h][3].x;
        o[2*i+1] = w00 * hv[h][0].y + w01 * hv[h][1].y + w10 * hv[h][2].y + w11 * hv[h][3].y;
    }

    // 32 contiguous floats per point -> 8x float4 PLAIN stores.
    // (nt-stores caused 2.7x write amplification: 16B no-allocate chunks don't
    //  merge into full lines. Byte-masked write-back L2 merges these for free.)
    vfloat4* op = (vfloat4*)(out + (size_t)p * (2 * NLEVELS));
#pragma unroll
    for (int j = 0; j < 8; ++j) {
        vfloat4 w;
        w.x = o[4 * j + 0];
        w.y = o[4 * j + 1];
        w.z = o[4 * j + 2];
        w.w = o[4 * j + 3];
        op[j] = w;
    }
}

static void compute_meta(Meta& m)
{
    // EXACTLY mirror the Python reference's double-precision math (same libm):
    // b = exp((log(2048) - log(16)) / 15); res_i = int(16 * b**i)
    const double b = exp((log(2048.0) - log(16.0)) / 15.0);
    int off = 0;
    const long long T = 1LL << TBITS;
    for (int i = 0; i < NLEVELS; ++i) {
        int res = (int)(16.0 * pow(b, (double)i));
        long long n_entries = (long long)(res + 1) * (long long)(res + 1);
        if (n_entries > T) n_entries = T;
        m.resf[i] = (float)res;
        m.resi[i] = res;
        m.off[i]  = off;
        off += (int)n_entries;
    }

    // smallest prime >= 2^17
    int pr = 1 << 17;
    for (;;) {
        bool isp = true;
        for (long long q = 2; q * q <= pr; ++q)
            if (pr % q == 0) { isp = false; break; }
        if (isp) break;
        ++pr;
    }
    m.prime = pr;
}

extern "C" void kernel_launch(void* const* d_in, const int* in_sizes, int n_in,
                              void* d_out, int out_size, void* d_ws, size_t ws_size,
                              hipStream_t stream)
{
    const float2* uv  = (const float2*)d_in[0];
    const float2* lat = (const float2*)d_in[1];
    float* out = (float*)d_out;

    int n = in_sizes[0] / 2;  // number of points

    Meta m;
    compute_meta(m);

    const int block = 256;
    const int grid = (n + block - 1) / block;
    hashgrid2d_kernel<<<grid, block, 0, stream>>>(uv, lat, out, m, n);
}

// Round 5
// 338.235 us; speedup vs baseline: 1.2534x; 1.0554x over previous
//
#include <hip/hip_runtime.h>
#include <math.h>

#define NLEVELS 16
#define NDENSE 12   // levels 0-11: (res+1)^2 <= 2^19, dense (structurally stable)
#define NHASH 4     // levels 12-15: hashed
#define TBITS 19
#define TMASK ((1 << TBITS) - 1)

typedef float vfloat4 __attribute__((ext_vector_type(4)));

struct Meta {
    float resf[NLEVELS];
    int   resi[NLEVELS];
    int   off[NLEVELS];   // entry offsets (in float2 units)
    int   prime;
};

__global__ __launch_bounds__(256, 1) void hashgrid2d_kernel(
    const float2* __restrict__ uv,
    const float2* __restrict__ lat,   // latents as float2 entries (F=2)
    float* __restrict__ out,
    Meta m, int n)
{
    int p = blockIdx.x * blockDim.x + threadIdx.x;
    if (p >= n) return;

    float2 u = uv[p];
    const float* latf = (const float*)lat;

    // Per-level latent data, statically indexed so it lives in registers.
    float4 da[NDENSE];      // dense corners (x0,y0),(x0,y1)
    float4 db[NDENSE];      // dense corners (x1,y0),(x1,y1)
    float2 hv[NHASH][4];    // hashed corners

    // ---- Phase 1: compute addresses and ISSUE ALL 40 LOADS ----
    // Latency-bound kernel (R4: VALUBusy 4.7%, HBM 36%): maximize per-wave MLP.
#pragma unroll
    for (int i = 0; i < NDENSE; ++i) {
        float sx = u.x * m.resf[i];
        float sy = u.y * m.resf[i];
        int x0 = (int)floorf(sx);
        int y0 = (int)floorf(sy);
        int base0 = m.off[i] + x0 * m.resi[i] + y0;  // (x0,y0); (x0,y1) adjacent
        int base1 = base0 + m.resi[i];               // (x1,y0); (x1,y1) adjacent
        __builtin_memcpy(&da[i], latf + 2 * (size_t)base0, 16);  // 8B-aligned 16B load
        __builtin_memcpy(&db[i], latf + 2 * (size_t)base1, 16);
    }
#pragma unroll
    for (int h = 0; h < NHASH; ++h) {
        int i = NDENSE + h;
        float sx = u.x * m.resf[i];
        float sy = u.y * m.resf[i];
        int x0 = (int)floorf(sx);
        int y0 = (int)floorf(sy);
        int yp0 = y0 * m.prime;
        int yp1 = yp0 + m.prime;
        int x1  = x0 + 1;
        const float2* tbl = lat + m.off[i];
        hv[h][0] = tbl[(x0 ^ yp0) & TMASK];
        hv[h][1] = tbl[(x0 ^ yp1) & TMASK];
        hv[h][2] = tbl[(x1 ^ yp0) & TMASK];
        hv[h][3] = tbl[(x1 ^ yp1) & TMASK];
    }

    // Hard scheduling fence: nothing moves across. Forces ALL 40 load results
    // live here (~128 VGPRs) -> compiler cannot collapse MLP (R4 gave VGPR=36,
    // ~8 loads in flight). Occupancy drops to ~3 waves/SIMD; per-CU outstanding
    // loads ~3x. Backend still drains vmcnt incrementally in issue order below.
    __builtin_amdgcn_sched_barrier(0);

    // ---- Phase 2: weights + weighted sums, in ISSUE ORDER ----
    float o[2 * NLEVELS];
#pragma unroll
    for (int i = 0; i < NDENSE; ++i) {
        float sx = u.x * m.resf[i];
        float sy = u.y * m.resf[i];
        float fx = floorf(sx), fy = floorf(sy);
        float px = sx - fx,   py = sy - fy;
        float w00 = (1.0f - px) * (1.0f - py);
        float w01 = (1.0f - px) * py;
        float w10 = px * (1.0f - py);
        float w11 = px * py;
        o[2*i]   = w00 * da[i].x + w01 * da[i].z + w10 * db[i].x + w11 * db[i].z;
        o[2*i+1] = w00 * da[i].y + w01 * da[i].w + w10 * db[i].y + w11 * db[i].w;
    }
#pragma unroll
    for (int h = 0; h < NHASH; ++h) {
        int i = NDENSE + h;
        float sx = u.x * m.resf[i];
        float sy = u.y * m.resf[i];
        float fx = floorf(sx), fy = floorf(sy);
        float px = sx - fx,   py = sy - fy;
        float w00 = (1.0f - px) * (1.0f - py);
        float w01 = (1.0f - px) * py;
        float w10 = px * (1.0f - py);
        float w11 = px * py;
        o[2*i]   = w00 * hv[h][0].x + w01 * hv[h][1].x + w10 * hv[h][2].x + w11 * hv[h][3].x;
        o[2*i+1] = w00 * hv[h][0].y + w01 * hv[h][1].y + w10 * hv[h][2].y + w11 * hv[h][3].y;
    }

    // 32 contiguous floats per point -> 8x float4 PLAIN stores (nt-stores
    // caused 2.7x write amplification in R3; write-back L2 merges these).
    vfloat4* op = (vfloat4*)(out + (size_t)p * (2 * NLEVELS));
#pragma unroll
    for (int j = 0; j < 8; ++j) {
        vfloat4 w;
        w.x = o[4 * j + 0];
        w.y = o[4 * j + 1];
        w.z = o[4 * j + 2];
        w.w = o[4 * j + 3];
        op[j] = w;
    }
}

static void compute_meta(Meta& m)
{
    // EXACTLY mirror the Python reference's double-precision math (same libm):
    // b = exp((log(2048) - log(16)) / 15); res_i = int(16 * b**i)
    const double b = exp((log(2048.0) - log(16.0)) / 15.0);
    int off = 0;
    const long long T = 1LL << TBITS;
    for (int i = 0; i < NLEVELS; ++i) {
        int res = (int)(16.0 * pow(b, (double)i));
        long long n_entries = (long long)(res + 1) * (long long)(res + 1);
        if (n_entries > T) n_entries = T;
        m.resf[i] = (float)res;
        m.resi[i] = res;
        m.off[i]  = off;
        off += (int)n_entries;
    }

    // smallest prime >= 2^17
    int pr = 1 << 17;
    for (;;) {
        bool isp = true;
        for (long long q = 2; q * q <= pr; ++q)
            if (pr % q == 0) { isp = false; break; }
        if (isp) break;
        ++pr;
    }
    m.prime = pr;
}

extern "C" void kernel_launch(void* const* d_in, const int* in_sizes, int n_in,
                              void* d_out, int out_size, void* d_ws, size_t ws_size,
                              hipStream_t stream)
{
    const float2* uv  = (const float2*)d_in[0];
    const float2* lat = (const float2*)d_in[1];
    float* out = (float*)d_out;

    int n = in_sizes[0] / 2;  // number of points

    Meta m;
    compute_meta(m);

    const int block = 256;
    const int grid = (n + block - 1) / block;
    hashgrid2d_kernel<<<grid, block, 0, stream>>>(uv, lat, out, m, n);
}

// Round 6
// 306.536 us; speedup vs baseline: 1.3830x; 1.1034x over previous
//
#include <hip/hip_runtime.h>
#include <math.h>

#define NLEVELS 16
#define NDENSE 12   // levels 0-11 dense; 12-15 hashed (structurally stable)
#define NHASH 4
#define TBITS 19
#define TMASK ((1 << TBITS) - 1)

typedef float vfloat4 __attribute__((ext_vector_type(4)));

struct Meta {
    float resf[NLEVELS];
    int   resi[NLEVELS];
    int   off[NLEVELS];   // entry offsets (float2 units)
    int   prime;
};

// ---- Phase kernels: one hashed level per launch. While this kernel runs,
// every XCD's 4 MB L2 holds exactly this level's 4 MB table -> gathers are
// L2 hits (~200cy) instead of L3 round-trips (~700cy). Results packed
// coalesced into ws (level-major) to avoid partial-line writes to out.
__global__ void hash_level_kernel(
    const float2* __restrict__ uv,
    const float2* __restrict__ lat,
    float2* __restrict__ ws_out,   // [n] packed result for this level
    float resf, int off, int prime, int n)
{
    int p = blockIdx.x * blockDim.x + threadIdx.x;
    if (p >= n) return;
    float2 u = uv[p];
    float sx = u.x * resf, sy = u.y * resf;
    float fx = floorf(sx), fy = floorf(sy);
    int x0 = (int)fx, y0 = (int)fy;
    float px = sx - fx, py = sy - fy;
    int yp0 = y0 * prime;
    int yp1 = yp0 + prime;
    const float2* tb = lat + off;
    float2 c00 = tb[(x0 ^ yp0) & TMASK];
    float2 c01 = tb[(x0 ^ yp1) & TMASK];
    float2 c10 = tb[((x0 + 1) ^ yp0) & TMASK];  // even x0: idx = h00^1, same line -> MSHR merge
    float2 c11 = tb[((x0 + 1) ^ yp1) & TMASK];
    float w00 = (1.0f - px) * (1.0f - py);
    float w01 = (1.0f - px) * py;
    float w10 = px * (1.0f - py);
    float w11 = px * py;
    float2 r;
    r.x = w00 * c00.x + w01 * c01.x + w10 * c10.x + w11 * c11.x;
    r.y = w00 * c00.y + w01 * c01.y + w10 * c10.y + w11 * c11.y;
    ws_out[p] = r;
}

// ---- Dense levels + final assembly (reads packed hashed results from ws,
// writes each 128B output line exactly once, fully coalesced).
__global__ __launch_bounds__(256, 1) void dense_assemble_kernel(
    const float2* __restrict__ uv,
    const float2* __restrict__ lat,
    const float2* __restrict__ ws,   // [NHASH][n] level-major
    float* __restrict__ out,
    Meta m, int n)
{
    int p = blockIdx.x * blockDim.x + threadIdx.x;
    if (p >= n) return;

    float2 u = uv[p];
    const float* latf = (const float*)lat;

    float4 da[NDENSE];
    float4 db[NDENSE];
    float2 hres[NHASH];

    // Issue all loads up front (latency-bound: maximize per-wave MLP).
#pragma unroll
    for (int i = 0; i < NDENSE; ++i) {
        float sx = u.x * m.resf[i];
        float sy = u.y * m.resf[i];
        int x0 = (int)floorf(sx);
        int y0 = (int)floorf(sy);
        int base0 = m.off[i] + x0 * m.resi[i] + y0;  // (x0,y0),(x0,y1) adjacent
        int base1 = base0 + m.resi[i];               // (x1,y0),(x1,y1) adjacent
        __builtin_memcpy(&da[i], latf + 2 * (size_t)base0, 16);
        __builtin_memcpy(&db[i], latf + 2 * (size_t)base1, 16);
    }
#pragma unroll
    for (int h = 0; h < NHASH; ++h)
        hres[h] = ws[(size_t)h * n + p];

    __builtin_amdgcn_sched_barrier(0);

    float o[2 * NLEVELS];
#pragma unroll
    for (int i = 0; i < NDENSE; ++i) {
        float sx = u.x * m.resf[i];
        float sy = u.y * m.resf[i];
        float fx = floorf(sx), fy = floorf(sy);
        float px = sx - fx,   py = sy - fy;
        float w00 = (1.0f - px) * (1.0f - py);
        float w01 = (1.0f - px) * py;
        float w10 = px * (1.0f - py);
        float w11 = px * py;
        o[2*i]   = w00 * da[i].x + w01 * da[i].z + w10 * db[i].x + w11 * db[i].z;
        o[2*i+1] = w00 * da[i].y + w01 * da[i].w + w10 * db[i].y + w11 * db[i].w;
    }
#pragma unroll
    for (int h = 0; h < NHASH; ++h) {
        o[2*(NDENSE+h)]   = hres[h].x;
        o[2*(NDENSE+h)+1] = hres[h].y;
    }

    vfloat4* op = (vfloat4*)(out + (size_t)p * (2 * NLEVELS));
#pragma unroll
    for (int j = 0; j < 8; ++j) {
        vfloat4 w;
        w.x = o[4*j+0]; w.y = o[4*j+1]; w.z = o[4*j+2]; w.w = o[4*j+3];
        op[j] = w;
    }
}

// ---- Fallback: single monolithic kernel (R5 structure) if ws is too small.
__global__ __launch_bounds__(256, 1) void hashgrid2d_mono_kernel(
    const float2* __restrict__ uv,
    const float2* __restrict__ lat,
    float* __restrict__ out,
    Meta m, int n)
{
    int p = blockIdx.x * blockDim.x + threadIdx.x;
    if (p >= n) return;
    float2 u = uv[p];
    const float* latf = (const float*)lat;
    float4 da[NDENSE];
    float4 db[NDENSE];
    float2 hv[NHASH][4];
#pragma unroll
    for (int i = 0; i < NDENSE; ++i) {
        float sx = u.x * m.resf[i];
        float sy = u.y * m.resf[i];
        int x0 = (int)floorf(sx);
        int y0 = (int)floorf(sy);
        int base0 = m.off[i] + x0 * m.resi[i] + y0;
        int base1 = base0 + m.resi[i];
        __builtin_memcpy(&da[i], latf + 2 * (size_t)base0, 16);
        __builtin_memcpy(&db[i], latf + 2 * (size_t)base1, 16);
    }
#pragma unroll
    for (int h = 0; h < NHASH; ++h) {
        int i = NDENSE + h;
        float sx = u.x * m.resf[i];
        float sy = u.y * m.resf[i];
        int x0 = (int)floorf(sx);
        int y0 = (int)floorf(sy);
        int yp0 = y0 * m.prime;
        int yp1 = yp0 + m.prime;
        const float2* tb = lat + m.off[i];
        hv[h][0] = tb[(x0 ^ yp0) & TMASK];
        hv[h][1] = tb[(x0 ^ yp1) & TMASK];
        hv[h][2] = tb[((x0+1) ^ yp0) & TMASK];
        hv[h][3] = tb[((x0+1) ^ yp1) & TMASK];
    }
    __builtin_amdgcn_sched_barrier(0);
    float o[2 * NLEVELS];
#pragma unroll
    for (int i = 0; i < NDENSE; ++i) {
        float sx = u.x * m.resf[i];
        float sy = u.y * m.resf[i];
        float fx = floorf(sx), fy = floorf(sy);
        float px = sx - fx,   py = sy - fy;
        float w00 = (1.0f - px) * (1.0f - py);
        float w01 = (1.0f - px) * py;
        float w10 = px * (1.0f - py);
        float w11 = px * py;
        o[2*i]   = w00 * da[i].x + w01 * da[i].z + w10 * db[i].x + w11 * db[i].z;
        o[2*i+1] = w00 * da[i].y + w01 * da[i].w + w10 * db[i].y + w11 * db[i].w;
    }
#pragma unroll
    for (int h = 0; h < NHASH; ++h) {
        int i = NDENSE + h;
        float sx = u.x * m.resf[i];
        float sy = u.y * m.resf[i];
        float fx = floorf(sx), fy = floorf(sy);
        float px = sx - fx,   py = sy - fy;
        float w00 = (1.0f - px) * (1.0f - py);
        float w01 = (1.0f - px) * py;
        float w10 = px * (1.0f - py);
        float w11 = px * py;
        o[2*i]   = w00*hv[h][0].x + w01*hv[h][1].x + w10*hv[h][2].x + w11*hv[h][3].x;
        o[2*i+1] = w00*hv[h][0].y + w01*hv[h][1].y + w10*hv[h][2].y + w11*hv[h][3].y;
    }
    vfloat4* op = (vfloat4*)(out + (size_t)p * (2 * NLEVELS));
#pragma unroll
    for (int j = 0; j < 8; ++j) {
        vfloat4 w;
        w.x = o[4*j+0]; w.y = o[4*j+1]; w.z = o[4*j+2]; w.w = o[4*j+3];
        op[j] = w;
    }
}

static void compute_meta(Meta& m)
{
    // EXACTLY mirror the Python reference's double-precision math (same libm):
    const double b = exp((log(2048.0) - log(16.0)) / 15.0);
    int off = 0;
    const long long T = 1LL << TBITS;
    for (int i = 0; i < NLEVELS; ++i) {
        int res = (int)(16.0 * pow(b, (double)i));
        long long n_entries = (long long)(res + 1) * (long long)(res + 1);
        if (n_entries > T) n_entries = T;
        m.resf[i] = (float)res;
        m.resi[i] = res;
        m.off[i]  = off;
        off += (int)n_entries;
    }
    int pr = 1 << 17;
    for (;;) {
        bool isp = true;
        for (long long q = 2; q * q <= pr; ++q)
            if (pr % q == 0) { isp = false; break; }
        if (isp) break;
        ++pr;
    }
    m.prime = pr;
}

extern "C" void kernel_launch(void* const* d_in, const int* in_sizes, int n_in,
                              void* d_out, int out_size, void* d_ws, size_t ws_size,
                              hipStream_t stream)
{
    const float2* uv  = (const float2*)d_in[0];
    const float2* lat = (const float2*)d_in[1];
    float* out = (float*)d_out;

    int n = in_sizes[0] / 2;

    Meta m;
    compute_meta(m);

    const int block = 256;
    const int grid = (n + block - 1) / block;

    size_t ws_needed = (size_t)NHASH * (size_t)n * sizeof(float2);
    if (ws_size >= ws_needed) {
        // Phased: one kernel per hashed level (4 MB table == one XCD L2, so
        // gathers hit L2), serialized by stream order; then dense+assemble.
        float2* wsf = (float2*)d_ws;
        for (int h = 0; h < NHASH; ++h) {
            int i = NDENSE + h;
            hash_level_kernel<<<grid, block, 0, stream>>>(
                uv, lat, wsf + (size_t)h * n, m.resf[i], m.off[i], m.prime, n);
        }
        dense_assemble_kernel<<<grid, block, 0, stream>>>(uv, lat, wsf, out, m, n);
    } else {
        hashgrid2d_mono_kernel<<<grid, block, 0, stream>>>(uv, lat, out, m, n);
    }
}